// Round 7
// baseline (226.473 us; speedup 1.0000x reference)
//
#include <hip/hip_runtime.h>

#define GX 200
#define GY 200
#define GZ 16
#define NVOX (GX*GY*GZ)
#define NFEAT 8

#define NTX 50
#define NTY 50
#define NTILES (NTX*NTY)      // 2500 xy-tiles of 4x4 voxels
#define NSLAB 4               // z split into 4 slabs of 4 voxels
#define NBIN (NTILES*NSLAB)   // 10000 bins
#define CAP 160               // per-bin capacity (avg ~25)

#define NBLK 512              // fused kernel grid: 2 blocks/CU, co-residency guaranteed

// ws layout (ints):
//   [0, NBIN)            counts
//   [NBIN, NBIN+4)       grid-barrier counter (+pad to 16B-align buckets)
//   [NBIN+4, ...)        buckets (int2 {gauss id, packed lane-mask})
//   then records (5 float4 per gaussian)
#define WS_COUNTS 0
#define WS_BAR    NBIN
#define WS_BUCKETS (NBIN + 4)
#define WS_RECORDS (NBIN + 4 + NBIN*CAP*2)   // 3,210,004 ints; *4 bytes %16 == 0

// record: q0=(A00,A01,A02,A11) q1=(A12,A22,opac,mx)
//         q2=(my,mz,f0,f1)     q3=(f2,f3,f4,f5)    q4=(f6,f7,0,0)

__global__ __launch_bounds__(256) void fused_kernel(
    const float* __restrict__ means, const float* __restrict__ opac,
    const float* __restrict__ cov, const float* __restrict__ feat,
    int* __restrict__ ws, float4* __restrict__ recs,
    float* __restrict__ dens_out, float* __restrict__ feat_out, int G)
{
    const int tid = threadIdx.x;

    // ---------------- Phase A: prep records + bin into buckets ----------------
    for (int i = blockIdx.x*256 + tid; i < G*16; i += NBLK*256) {
        const int g = i >> 4, s = i & 15;

        const float lox = -40.f, loy = -40.f, loz = -1.f;
        const float hix =  40.f, hiy =  40.f, hiz =  5.4f;
        const float mx = means[g*3+0], my = means[g*3+1], mz = means[g*3+2];
        const float c00 = cov[g*9+0], c01 = cov[g*9+1], c02 = cov[g*9+2];
        const float c10 = cov[g*9+3], c11 = cov[g*9+4], c12 = cov[g*9+5];
        const float c20 = cov[g*9+6], c21 = cov[g*9+7], c22 = cov[g*9+8];

        const float sx = sqrtf(c00), sy = sqrtf(c11), sz = sqrtf(c22);
        const float blx = mx - 3.0f*sx, bly = my - 3.0f*sy, blz = mz - 3.0f*sz;
        const float bhx = mx + 3.0f*sx, bhy = my + 3.0f*sy, bhz = mz + 3.0f*sz;
        const bool valid = (bhx > lox) & (bhy > loy) & (bhz > loz)
                         & (blx < hix) & (bly < hiy) & (blz < hiz);
        if (!valid) continue;

        float blxc = fminf(fmaxf(blx, lox), hix);
        float blyc = fminf(fmaxf(bly, loy), hiy);
        float blzc = fminf(fmaxf(blz, loz), hiz);
        float bhxc = fminf(fmaxf(bhx, lox), hix);
        float bhyc = fminf(fmaxf(bhy, loy), hiy);
        float bhzc = fminf(fmaxf(bhz, loz), hiz);
        int ilox = (int)((blxc - lox) / 0.4f);
        int iloy = (int)((blyc - loy) / 0.4f);
        int iloz = (int)((blzc - loz) / 0.4f);
        int ihix = (int)((bhxc - lox) / 0.4f);
        int ihiy = (int)((bhyc - loy) / 0.4f);
        int ihiz = (int)((bhzc - loz) / 0.4f);
        ilox = min(ilox, GX-1); iloy = min(iloy, GY-1); iloz = min(iloz, GZ-1);
        ihix = min(ihix, GX-1); ihiy = min(ihiy, GY-1); ihiz = min(ihiz, GZ-1);

        if (s < 5) {
            const float m00 = c11*c22 - c12*c21;
            const float m01 = c10*c22 - c12*c20;
            const float m02 = c10*c21 - c11*c20;
            const float det = c00*m00 - c01*m01 + c02*m02;
            const float idet = 1.0f / det;
            float4 q;
            if (s == 0) {
                q.x = m00 * idet;
                q.y = (c02*c21 - c01*c22) * idet;
                q.z = (c01*c12 - c02*c11) * idet;
                q.w = (c00*c22 - c02*c20) * idet;
            } else if (s == 1) {
                q.x = (c02*c10 - c00*c12) * idet;
                q.y = (c00*c11 - c01*c10) * idet;
                q.z = opac[g];
                q.w = mx;
            } else if (s == 2) {
                q.x = my; q.y = mz;
                q.z = feat[g*8+0]; q.w = feat[g*8+1];
            } else if (s == 3) {
                q.x = feat[g*8+2]; q.y = feat[g*8+3]; q.z = feat[g*8+4]; q.w = feat[g*8+5];
            } else {
                q.x = feat[g*8+6]; q.y = feat[g*8+7]; q.z = 0.f; q.w = 0.f;
            }
            recs[(size_t)g*5 + s] = q;
        }

        const int txlo = ilox >> 2, txhi = ihix >> 2;
        const int tylo = iloy >> 2, tyhi = ihiy >> 2;
        const int tx = txlo + (s >> 2);
        const int ty = tylo + (s & 3);
        if (tx <= txhi && ty <= tyhi) {
            const int lxlo = max(ilox - tx*4, 0), lxhi = min(ihix - tx*4, 3);
            const int lylo = max(iloy - ty*4, 0), lyhi = min(ihiy - ty*4, 3);
            const int xm = ((1 << (lxhi+1)) - 1) & ~((1 << lxlo) - 1);
            const int ym = ((1 << (lyhi+1)) - 1) & ~((1 << lylo) - 1);
            const int spread = (xm & 1) + (xm & 2)*8 + (xm & 4)*64 + (xm & 8)*512;
            const int xymask = ym * spread;

            const int slo = iloz >> 2, shi = ihiz >> 2;
            const int base = (tx*NTY + ty)*NSLAB;
            int2* __restrict__ bkt = (int2*)(ws + WS_BUCKETS);
            for (int sl = slo; sl <= shi; ++sl) {
                const int lzlo = max(iloz - sl*4, 0), lzhi = min(ihiz - sl*4, 3);
                const int zm = ((1 << (lzhi+1)) - 1) & ~((1 << lzlo) - 1);
                const int pos = atomicAdd(&ws[WS_COUNTS + base + sl], 1);
                if (pos < CAP) {
                    int2 e; e.x = g; e.y = xymask | (zm << 16);
                    bkt[(size_t)(base + sl)*CAP + pos] = e;
                }
            }
        }
    }

    // ---------------- Phase B: device-scope grid barrier ----------------
    // ws[WS_BAR] was zeroed by the preceding memset; all NBLK blocks are
    // co-resident (2 blocks/CU, no LDS, <128 VGPR) so spinning is safe.
    __syncthreads();
    if (tid == 0) {
        __threadfence();                        // publish phase-A writes
        atomicAdd(&ws[WS_BAR], 1);
        while (__hip_atomic_load(&ws[WS_BAR], __ATOMIC_ACQUIRE,
                                 __HIP_MEMORY_SCOPE_AGENT) < NBLK) {
            __builtin_amdgcn_s_sleep(1);
        }
    }
    __syncthreads();
    __threadfence();                            // acquire phase-A writes

    // ---------------- Phase C: gather, one bin per wave (grid-stride) --------
    const int wv = blockIdx.x*4 + (tid >> 6);   // global wave id, 0..NBLK*4
    const int l = tid & 63;
    const int lx = l >> 4, ly = (l >> 2) & 3, lz = l & 3;
    const int sh_xy = lx*4 + ly;
    const int sh_z  = 16 + lz;

    for (int bin = wv; bin < NBIN; bin += NBLK*4) {
        const int tile = bin >> 2, slab = bin & 3;
        const int tx = tile / NTY, ty = tile % NTY;
        const int ix = tx*4 + lx, iy = ty*4 + ly, iz = slab*4 + lz;

        const float cx = ((float)ix + 0.5f) * 0.4f + (-40.f);
        const float cy = ((float)iy + 0.5f) * 0.4f + (-40.f);
        const float cz = ((float)iz + 0.5f) * 0.4f + (-1.f);

        const int n = min(ws[WS_COUNTS + bin], CAP);
        const int2* __restrict__ bkt = (const int2*)(ws + WS_BUCKETS) + (size_t)bin*CAP;

        float den = 0.f;
        float2 a01 = {0.f,0.f}, a23 = {0.f,0.f}, a45 = {0.f,0.f}, a67 = {0.f,0.f};

        int2 e = (n > 0) ? bkt[0] : int2{0,0};
        for (int j = 0; j < n; ++j) {
            const int g = __builtin_amdgcn_readfirstlane(e.x);
            const int msk = e.y;
            if (j + 1 < n) e = bkt[j + 1];
            const float4* __restrict__ r = recs + (size_t)g * 5;
            const float4 q0 = r[0], q1 = r[1], q2 = r[2], q3 = r[3];
            const float2 q4 = *(const float2*)(r + 4);

            const bool in = ((msk >> sh_xy) & (msk >> sh_z) & 1) != 0;

            const float X = cx - q1.w, Y = cy - q2.x, Z = cz - q2.y;
            const float maha = q0.x*X*X + q0.w*Y*Y + q1.y*Z*Z
                             + 2.0f*(q0.y*X*Y + q0.z*X*Z + q1.x*Y*Z);
            float wgt = q1.z * __expf(-0.5f * maha);
            wgt = in ? wgt : 0.f;
            den += wgt;
            a01.x += wgt*q2.z; a01.y += wgt*q2.w;
            a23.x += wgt*q3.x; a23.y += wgt*q3.y;
            a45.x += wgt*q3.z; a45.y += wgt*q3.w;
            a67.x += wgt*q4.x; a67.y += wgt*q4.y;
        }

        const int flat = (ix*GY + iy)*GZ + iz;
        dens_out[flat] = den;
        const float dc = fmaxf(den, 1e-6f);
        float4 fa, fb;
        fa.x = a01.x/dc; fa.y = a01.y/dc; fa.z = a23.x/dc; fa.w = a23.y/dc;
        fb.x = a45.x/dc; fb.y = a45.y/dc; fb.z = a67.x/dc; fb.w = a67.y/dc;
        float4* fp = (float4*)(feat_out + (size_t)flat * NFEAT);
        fp[0] = fa; fp[1] = fb;
    }
}

extern "C" void kernel_launch(void* const* d_in, const int* in_sizes, int n_in,
                              void* d_out, int out_size, void* d_ws, size_t ws_size,
                              hipStream_t stream) {
    const float* means = (const float*)d_in[0];
    const float* opac  = (const float*)d_in[1];
    const float* cov   = (const float*)d_in[2];
    const float* feat  = (const float*)d_in[3];
    const int G = in_sizes[0] / 3;

    float* dens_out = (float*)d_out;
    float* feat_out = dens_out + NVOX;
    int* ws = (int*)d_ws;
    float4* recs = (float4*)((char*)d_ws + (size_t)WS_RECORDS * sizeof(int));

    // zero counts + barrier counter (re-armed every replay; poison-safe)
    hipMemsetAsync(ws, 0, (NBIN + 4) * sizeof(int), stream);
    fused_kernel<<<NBLK, 256, 0, stream>>>(means, opac, cov, feat, ws, recs,
                                           dens_out, feat_out, G);
}

// Round 8
// 100.684 us; speedup vs baseline: 2.2494x; 2.2494x over previous
//
#include <hip/hip_runtime.h>

#define GX 200
#define GY 200
#define GZ 16
#define NVOX (GX*GY*GZ)
#define NFEAT 8

#define NTX 50
#define NTY 50
#define NTILES (NTX*NTY)      // 2500 xy-tiles of 4x4 voxels
#define NSLAB 4               // z split into 4 slabs of 4 voxels
#define NBIN (NTILES*NSLAB)   // 10000 bins
#define CAP 160               // per-bin capacity (avg ~25)

// ws layout (ints):
//   [0, NBIN)                     counts
//   [NBIN, NBIN + NBIN*CAP*2)     buckets (int2: {gauss id, packed lane-mask})
//   records: 5 float4 per gaussian
#define WS_COUNTS 0
#define WS_BUCKETS NBIN
#define WS_RECORDS (NBIN + NBIN*CAP*2)   // 3,210,000 ints -> 16B aligned

// record: q0=(A00,A01,A02,A11) q1=(A12,A22,opac,mx)
//         q2=(my,mz,f0,f1)     q3=(f2,f3,f4,f5)    q4=(f6,f7,0,0)

__global__ __launch_bounds__(256) void prep_fill_kernel(
    const float* __restrict__ means, const float* __restrict__ opac,
    const float* __restrict__ cov, const float* __restrict__ feat,
    int* __restrict__ ws, float4* __restrict__ recs, int G)
{
    const int i = blockIdx.x*256 + threadIdx.x;
    const int g = i >> 4, s = i & 15;
    if (g >= G) return;

    const float lox = -40.f, loy = -40.f, loz = -1.f;
    const float hix =  40.f, hiy =  40.f, hiz =  5.4f;
    const float mx = means[g*3+0], my = means[g*3+1], mz = means[g*3+2];
    const float c00 = cov[g*9+0], c01 = cov[g*9+1], c02 = cov[g*9+2];
    const float c10 = cov[g*9+3], c11 = cov[g*9+4], c12 = cov[g*9+5];
    const float c20 = cov[g*9+6], c21 = cov[g*9+7], c22 = cov[g*9+8];

    const float sx = sqrtf(c00), sy = sqrtf(c11), sz = sqrtf(c22);
    const float blx = mx - 3.0f*sx, bly = my - 3.0f*sy, blz = mz - 3.0f*sz;
    const float bhx = mx + 3.0f*sx, bhy = my + 3.0f*sy, bhz = mz + 3.0f*sz;
    const bool valid = (bhx > lox) & (bhy > loy) & (bhz > loz)
                     & (blx < hix) & (bly < hiy) & (blz < hiz);
    if (!valid) return;

    float blxc = fminf(fmaxf(blx, lox), hix);
    float blyc = fminf(fmaxf(bly, loy), hiy);
    float blzc = fminf(fmaxf(blz, loz), hiz);
    float bhxc = fminf(fmaxf(bhx, lox), hix);
    float bhyc = fminf(fmaxf(bhy, loy), hiy);
    float bhzc = fminf(fmaxf(bhz, loz), hiz);
    int ilox = (int)((blxc - lox) / 0.4f);
    int iloy = (int)((blyc - loy) / 0.4f);
    int iloz = (int)((blzc - loz) / 0.4f);
    int ihix = (int)((bhxc - lox) / 0.4f);
    int ihiy = (int)((bhyc - loy) / 0.4f);
    int ihiz = (int)((bhzc - loz) / 0.4f);
    ilox = min(ilox, GX-1); iloy = min(iloy, GY-1); iloz = min(iloz, GZ-1);
    ihix = min(ihix, GX-1); ihiy = min(ihiy, GY-1); ihiz = min(ihiz, GZ-1);

    // record write: lanes s=0..4 each store one float4 (contiguous 80 B)
    if (s < 5) {
        const float m00 = c11*c22 - c12*c21;
        const float m01 = c10*c22 - c12*c20;
        const float m02 = c10*c21 - c11*c20;
        const float det = c00*m00 - c01*m01 + c02*m02;
        const float idet = 1.0f / det;
        float4 q;
        if (s == 0) {
            q.x = m00 * idet;
            q.y = (c02*c21 - c01*c22) * idet;
            q.z = (c01*c12 - c02*c11) * idet;
            q.w = (c00*c22 - c02*c20) * idet;
        } else if (s == 1) {
            q.x = (c02*c10 - c00*c12) * idet;
            q.y = (c00*c11 - c01*c10) * idet;
            q.z = opac[g];
            q.w = mx;
        } else if (s == 2) {
            q.x = my;
            q.y = mz;
            q.z = feat[g*8+0];
            q.w = feat[g*8+1];
        } else if (s == 3) {
            q.x = feat[g*8+2]; q.y = feat[g*8+3]; q.z = feat[g*8+4]; q.w = feat[g*8+5];
        } else {
            q.x = feat[g*8+6]; q.y = feat[g*8+7]; q.z = 0.f; q.w = 0.f;
        }
        recs[(size_t)g*5 + s] = q;
    }

    // binning: slot (s>>2, s&3) covers xy-tile (txlo + s>>2, tylo + s&3)
    const int txlo = ilox >> 2, txhi = ihix >> 2;
    const int tylo = iloy >> 2, tyhi = ihiy >> 2;
    const int tx = txlo + (s >> 2);
    const int ty = tylo + (s & 3);
    if (tx <= txhi && ty <= tyhi) {
        // per-(gaussian,tile) xy lane mask: bit (lx*4+ly) set iff voxel in box
        const int lxlo = max(ilox - tx*4, 0), lxhi = min(ihix - tx*4, 3);
        const int lylo = max(iloy - ty*4, 0), lyhi = min(ihiy - ty*4, 3);
        const int xm = ((1 << (lxhi+1)) - 1) & ~((1 << lxlo) - 1);   // 4 bits
        const int ym = ((1 << (lyhi+1)) - 1) & ~((1 << lylo) - 1);   // 4 bits
        const int spread = (xm & 1) + (xm & 2)*8 + (xm & 4)*64 + (xm & 8)*512;
        const int xymask = ym * spread;                               // 16 bits

        const int slo = iloz >> 2, shi = ihiz >> 2;
        const int base = (tx*NTY + ty)*NSLAB;
        int2* __restrict__ bkt = (int2*)(ws + WS_BUCKETS);
        for (int sl = slo; sl <= shi; ++sl) {
            const int lzlo = max(iloz - sl*4, 0), lzhi = min(ihiz - sl*4, 3);
            const int zm = ((1 << (lzhi+1)) - 1) & ~((1 << lzlo) - 1);
            const int pos = atomicAdd(&ws[WS_COUNTS + base + sl], 1);
            if (pos < CAP) {
                int2 e; e.x = g; e.y = xymask | (zm << 16);
                bkt[(size_t)(base + sl)*CAP + pos] = e;
            }
        }
    }
}

__global__ __launch_bounds__(256) void gather_kernel(
    const int* __restrict__ ws, const float4* __restrict__ recs,
    float* __restrict__ dens_out, float* __restrict__ feat_out)
{
    const int tile = blockIdx.x;
    const int tx = tile / NTY, ty = tile % NTY;
    const int t = threadIdx.x;
    const int w = t >> 6, l = t & 63;          // wave w owns z-slab [4w, 4w+4)
    const int lx = l >> 4, ly = (l >> 2) & 3, lz = l & 3;
    const int ix = tx*4 + lx, iy = ty*4 + ly, iz = w*4 + lz;
    const int sh_xy = lx*4 + ly;               // bit index in xymask
    const int sh_z  = 16 + lz;                 // bit index of zmask

    const float cx = ((float)ix + 0.5f) * 0.4f + (-40.f);
    const float cy = ((float)iy + 0.5f) * 0.4f + (-40.f);
    const float cz = ((float)iz + 0.5f) * 0.4f + (-1.f);

    const int bin = tile*NSLAB + w;
    const int n = min(ws[WS_COUNTS + bin], CAP);
    const int2* __restrict__ bkt = (const int2*)(ws + WS_BUCKETS) + (size_t)bin*CAP;

    float den = 0.f;
    float2 a01 = {0.f,0.f}, a23 = {0.f,0.f}, a45 = {0.f,0.f}, a67 = {0.f,0.f};

    int2 e = (n > 0) ? bkt[0] : int2{0,0};
    for (int j = 0; j < n; ++j) {
        const int g = __builtin_amdgcn_readfirstlane(e.x);
        const int msk = e.y;
        if (j + 1 < n) e = bkt[j + 1];          // prefetch next entry
        const float4* __restrict__ r = recs + (size_t)g * 5;
        const float4 q0 = r[0], q1 = r[1], q2 = r[2], q3 = r[3];
        const float2 q4 = *(const float2*)(r + 4);

        // 2-shift box test from precomputed lane masks
        const bool in = ((msk >> sh_xy) & (msk >> sh_z) & 1) != 0;

        const float X = cx - q1.w, Y = cy - q2.x, Z = cz - q2.y;
        const float maha = q0.x*X*X + q0.w*Y*Y + q1.y*Z*Z
                         + 2.0f*(q0.y*X*Y + q0.z*X*Z + q1.x*Y*Z);
        float wgt = q1.z * __expf(-0.5f * maha);
        wgt = in ? wgt : 0.f;
        den += wgt;
        a01.x += wgt*q2.z; a01.y += wgt*q2.w;   // f0,f1
        a23.x += wgt*q3.x; a23.y += wgt*q3.y;   // f2,f3
        a45.x += wgt*q3.z; a45.y += wgt*q3.w;   // f4,f5
        a67.x += wgt*q4.x; a67.y += wgt*q4.y;   // f6,f7
    }

    const int flat = (ix*GY + iy)*GZ + iz;
    dens_out[flat] = den;
    const float dc = fmaxf(den, 1e-6f);
    float4 fa, fb;
    fa.x = a01.x/dc; fa.y = a01.y/dc; fa.z = a23.x/dc; fa.w = a23.y/dc;
    fb.x = a45.x/dc; fb.y = a45.y/dc; fb.z = a67.x/dc; fb.w = a67.y/dc;
    float4* fp = (float4*)(feat_out + (size_t)flat * NFEAT);
    fp[0] = fa; fp[1] = fb;
}

extern "C" void kernel_launch(void* const* d_in, const int* in_sizes, int n_in,
                              void* d_out, int out_size, void* d_ws, size_t ws_size,
                              hipStream_t stream) {
    const float* means = (const float*)d_in[0];
    const float* opac  = (const float*)d_in[1];
    const float* cov   = (const float*)d_in[2];
    const float* feat  = (const float*)d_in[3];
    const int G = in_sizes[0] / 3;

    float* dens_out = (float*)d_out;
    float* feat_out = dens_out + NVOX;
    int* ws = (int*)d_ws;
    float4* recs = (float4*)((char*)d_ws + (size_t)WS_RECORDS * sizeof(int));

    hipMemsetAsync(ws, 0, NBIN * sizeof(int), stream);
    prep_fill_kernel<<<(G*16 + 255)/256, 256, 0, stream>>>(means, opac, cov, feat,
                                                           ws, recs, G);
    gather_kernel<<<NTILES, 256, 0, stream>>>(ws, recs, dens_out, feat_out);
}